// Round 5
// baseline (175.450 us; speedup 1.0000x reference)
//
#include <hip/hip_runtime.h>
#include <hip/hip_bf16.h>

#define N_SRC   131072
#define N_DST   65536
#define D       128      // D_IN == D_OUT == 128

typedef __bf16 bf16x8 __attribute__((ext_vector_type(8)));
typedef float  f32x4  __attribute__((ext_vector_type(4)));

#define CONV_BLOCKS 8192   // (N_SRC*D) / (256 threads * 8 elems) = 8192
#define W_BLOCKS    64     // 64*256 = 16384 = D*D elements

// ---------------------------------------------------------------------------
// Kernel 1 (fused prep): role-split grid.
//  blocks [0, CONV_BLOCKS)                : feat fp32 -> bf16 (streaming)
//  blocks [CONV_BLOCKS, CONV+n_bnd)       : sorted dst -> CSR row_start
//  blocks [CONV+n_bnd, CONV+n_bnd+64)     : W fp32 [k][n] -> Wt bf16 [n][k]
// ---------------------------------------------------------------------------
__global__ __launch_bounds__(256) void prep_kernel(
    const float* __restrict__ feat,
    const int*   __restrict__ dst, int n_edges, int n_bnd_blocks,
    const float* __restrict__ W_self, const float* __restrict__ W_neigh,
    __bf16* __restrict__ feat_bf,
    int*    __restrict__ row_start,
    __bf16* __restrict__ Wt_self, __bf16* __restrict__ Wt_neigh)
{
    const int b = blockIdx.x;
    const int t = threadIdx.x;

    if (b < CONV_BLOCKS) {
        const size_t i0 = ((size_t)b * 256 + t) * 8;
        const float4 a0 = *(const float4*)&feat[i0];
        const float4 a1 = *(const float4*)&feat[i0 + 4];
        bf16x8 o;
        o[0] = (__bf16)a0.x; o[1] = (__bf16)a0.y; o[2] = (__bf16)a0.z; o[3] = (__bf16)a0.w;
        o[4] = (__bf16)a1.x; o[5] = (__bf16)a1.y; o[6] = (__bf16)a1.z; o[7] = (__bf16)a1.w;
        *(bf16x8*)&feat_bf[i0] = o;
    } else if (b < CONV_BLOCKS + n_bnd_blocks) {
        const int e = (b - CONV_BLOCKS) * 256 + t;
        if (e < n_edges) {
            const int d    = dst[e];
            const int prev = (e == 0) ? -1 : dst[e - 1];
            for (int r = prev + 1; r <= d; ++r) row_start[r] = e;
            if (e == n_edges - 1)
                for (int r = d + 1; r <= N_DST; ++r) row_start[r] = n_edges;
        }
    } else {
        const int wb  = b - CONV_BLOCKS - n_bnd_blocks;  // 0..63
        const int idx = wb * 256 + t;                    // 0..16383
        const int k = idx >> 7, n = idx & 127;
        Wt_self [n * D + k] = (__bf16)W_self [k * D + n];
        Wt_neigh[n * D + k] = (__bf16)W_neigh[k * D + n];
    }
}

// ---------------------------------------------------------------------------
// Kernel 2 (FUSED neigh + gemm): no LDS, no barriers.
// Wave covers 16 dst rows. Lane l: row m = l&15, k-slice quad = l>>4.
// Gather phase: lane accumulates neighbor-sum of row m over columns
// ks*32 + quad*8 + j (ks=0..3, j=0..7) in fp32 -> scale by 1/deg -> bf16.
// That register layout IS the MFMA A-fragment layout (A[m][k=quad*8+j] per
// 32-wide k-chunk), so h_neigh never touches memory.
// GEMM phase: 2x (4 ks x 8 nb) MFMAs; self-phase A-frags loaded straight
// from feat_bf (contiguous 16 B per lane); B-frags from L2-hot Wt.
// Epilogue: C/D layout col=lane&15, row=quad*4+reg, + bias.
// ---------------------------------------------------------------------------
__global__ __launch_bounds__(256) void fused_kernel(
    const __bf16* __restrict__ feat_bf,
    const int*    __restrict__ src,
    const int*    __restrict__ row_start,
    const __bf16* __restrict__ Wt_self,   // bf16 [n][k]
    const __bf16* __restrict__ Wt_neigh,  // bf16 [n][k]
    const float*  __restrict__ b_self,
    const float*  __restrict__ b_neigh,
    float*        __restrict__ out)
{
    const int t    = threadIdx.x;
    const int w    = t >> 6;          // wave 0..3
    const int l    = t & 63;
    const int m16  = l & 15;
    const int quad = l >> 4;          // 0..3
    const int kb   = quad * 8;
    const int rowbase = blockIdx.x * 64 + w * 16;
    const int row  = rowbase + m16;

    // ---- gather phase: neighbor mean, accumulated in A-fragment layout ----
    const int s0 = row_start[row];
    const int s1 = row_start[row + 1];

    float accg[4][8];
    #pragma unroll
    for (int ks = 0; ks < 4; ++ks)
        #pragma unroll
        for (int j = 0; j < 8; ++j) accg[ks][j] = 0.f;

    for (int e = s0; e < s1; e += 4) {
        const int e1 = (e + 1 < s1) ? e + 1 : e;
        const int e2 = (e + 2 < s1) ? e + 2 : e;
        const int e3 = (e + 3 < s1) ? e + 3 : e;
        const int i0 = src[e];
        const int i1 = src[e1];
        const int i2 = src[e2];
        const int i3 = src[e3];
        bf16x8 v0[4], v1[4], v2[4], v3[4];
        #pragma unroll
        for (int ks = 0; ks < 4; ++ks) {
            const int off = ks * 32 + kb;
            v0[ks] = *(const bf16x8*)&feat_bf[(size_t)i0 * D + off];
            v1[ks] = *(const bf16x8*)&feat_bf[(size_t)i1 * D + off];
            v2[ks] = *(const bf16x8*)&feat_bf[(size_t)i2 * D + off];
            v3[ks] = *(const bf16x8*)&feat_bf[(size_t)i3 * D + off];
        }
        const float m1 = (e + 1 < s1) ? 1.f : 0.f;
        const float m2 = (e + 2 < s1) ? 1.f : 0.f;
        const float m3 = (e + 3 < s1) ? 1.f : 0.f;
        #pragma unroll
        for (int ks = 0; ks < 4; ++ks)
            #pragma unroll
            for (int j = 0; j < 8; ++j) {
                float a = accg[ks][j] + (float)v0[ks][j];
                a = fmaf(m1, (float)v1[ks][j], a);
                a = fmaf(m2, (float)v2[ks][j], a);
                a = fmaf(m3, (float)v3[ks][j], a);
                accg[ks][j] = a;
            }
    }

    const float inv = 1.0f / fmaxf((float)(s1 - s0), 1.0f);
    bf16x8 afragN[4];
    #pragma unroll
    for (int ks = 0; ks < 4; ++ks)
        #pragma unroll
        for (int j = 0; j < 8; ++j)
            afragN[ks][j] = (__bf16)(accg[ks][j] * inv);

    // ---- GEMM phase ------------------------------------------------------
    f32x4 acc[8];
    #pragma unroll
    for (int nb = 0; nb < 8; ++nb) acc[nb] = (f32x4){0.f, 0.f, 0.f, 0.f};

    // self: A from feat_bf
    #pragma unroll
    for (int ks = 0; ks < 4; ++ks) {
        const bf16x8 aS = *(const bf16x8*)&feat_bf[(size_t)row * D + ks * 32 + kb];
        #pragma unroll
        for (int nb = 0; nb < 8; ++nb) {
            const bf16x8 bS = *(const bf16x8*)&Wt_self[(size_t)(nb * 16 + m16) * D + ks * 32 + kb];
            acc[nb] = __builtin_amdgcn_mfma_f32_16x16x32_bf16(aS, bS, acc[nb], 0, 0, 0);
        }
    }
    // neigh: A from registers (afragN)
    #pragma unroll
    for (int ks = 0; ks < 4; ++ks) {
        #pragma unroll
        for (int nb = 0; nb < 8; ++nb) {
            const bf16x8 bN = *(const bf16x8*)&Wt_neigh[(size_t)(nb * 16 + m16) * D + ks * 32 + kb];
            acc[nb] = __builtin_amdgcn_mfma_f32_16x16x32_bf16(afragN[ks], bN, acc[nb], 0, 0, 0);
        }
    }

    // ---- epilogue --------------------------------------------------------
    #pragma unroll
    for (int nb = 0; nb < 8; ++nb) {
        const int col  = nb * 16 + m16;
        const float bias = b_self[col] + b_neigh[col];
        const int orow0 = rowbase + quad * 4;
        #pragma unroll
        for (int r = 0; r < 4; ++r)
            out[(size_t)(orow0 + r) * D + col] = acc[nb][r] + bias;
    }
}

// ---------------------------------------------------------------------------
extern "C" void kernel_launch(void* const* d_in, const int* in_sizes, int n_in,
                              void* d_out, int out_size, void* d_ws, size_t ws_size,
                              hipStream_t stream)
{
    const float* feat    = (const float*)d_in[0];
    const float* W_self  = (const float*)d_in[1];
    const float* b_self  = (const float*)d_in[2];
    const float* W_neigh = (const float*)d_in[3];
    const float* b_neigh = (const float*)d_in[4];
    const int*   src_idx = (const int*)d_in[5];
    const int*   dst_idx = (const int*)d_in[6];
    const int n_edges = in_sizes[5];

    // workspace layout
    char* ws = (char*)d_ws;
    __bf16* feat_bf   = (__bf16*)ws;                                 // 32 MB
    int*    row_start = (int*)(feat_bf + (size_t)N_SRC * D);         // 256 KB
    __bf16* Wt_self   = (__bf16*)(row_start + N_DST + 16);
    __bf16* Wt_neigh  = Wt_self + D * D;

    const int n_bnd = (n_edges + 255) / 256;
    prep_kernel<<<CONV_BLOCKS + n_bnd + W_BLOCKS, 256, 0, stream>>>(
        feat, dst_idx, n_edges, n_bnd, W_self, W_neigh,
        feat_bf, row_start, Wt_self, Wt_neigh);

    fused_kernel<<<N_DST / 64, 256, 0, stream>>>(
        feat_bf, src_idx, row_start, Wt_self, Wt_neigh, b_self, b_neigh,
        (float*)d_out);
}

// Round 6
// 173.952 us; speedup vs baseline: 1.0086x; 1.0086x over previous
//
#include <hip/hip_runtime.h>
#include <hip/hip_bf16.h>

#define N_SRC   131072
#define N_DST   65536
#define D       128      // D_IN == D_OUT == 128

typedef __bf16 bf16x8 __attribute__((ext_vector_type(8)));
typedef float  f32x4  __attribute__((ext_vector_type(4)));

#define CONV_BLOCKS 8192   // (N_SRC*D) / (256 threads * 8 elems) = 8192
#define W_BLOCKS    64     // 64*256 = 16384 = D*D elements

// LDS row pitch for the 16x128 bf16 h_neigh tile: +8 elems (16 B) pad
// -> row stride 272 B = 68 dwords -> 2-way bank aliasing only (free).
#define HPITCH 136

// ---------------------------------------------------------------------------
// Kernel 1 (fused prep): role-split grid.
//  blocks [0, CONV_BLOCKS)                : feat fp32 -> bf16 (streaming)
//  blocks [CONV_BLOCKS, CONV+n_bnd)       : sorted dst -> CSR row_start
//  blocks [CONV+n_bnd, CONV+n_bnd+64)     : W fp32 [k][n] -> Wt bf16 [n][k]
// ---------------------------------------------------------------------------
__global__ __launch_bounds__(256) void prep_kernel(
    const float* __restrict__ feat,
    const int*   __restrict__ dst, int n_edges, int n_bnd_blocks,
    const float* __restrict__ W_self, const float* __restrict__ W_neigh,
    __bf16* __restrict__ feat_bf,
    int*    __restrict__ row_start,
    __bf16* __restrict__ Wt_self, __bf16* __restrict__ Wt_neigh)
{
    const int b = blockIdx.x;
    const int t = threadIdx.x;

    if (b < CONV_BLOCKS) {
        const size_t i0 = ((size_t)b * 256 + t) * 8;
        const float4 a0 = *(const float4*)&feat[i0];
        const float4 a1 = *(const float4*)&feat[i0 + 4];
        bf16x8 o;
        o[0] = (__bf16)a0.x; o[1] = (__bf16)a0.y; o[2] = (__bf16)a0.z; o[3] = (__bf16)a0.w;
        o[4] = (__bf16)a1.x; o[5] = (__bf16)a1.y; o[6] = (__bf16)a1.z; o[7] = (__bf16)a1.w;
        *(bf16x8*)&feat_bf[i0] = o;
    } else if (b < CONV_BLOCKS + n_bnd_blocks) {
        const int e = (b - CONV_BLOCKS) * 256 + t;
        if (e < n_edges) {
            const int d    = dst[e];
            const int prev = (e == 0) ? -1 : dst[e - 1];
            for (int r = prev + 1; r <= d; ++r) row_start[r] = e;
            if (e == n_edges - 1)
                for (int r = d + 1; r <= N_DST; ++r) row_start[r] = n_edges;
        }
    } else {
        const int wb  = b - CONV_BLOCKS - n_bnd_blocks;  // 0..63
        const int idx = wb * 256 + t;                    // 0..16383
        const int k = idx >> 7, n = idx & 127;
        Wt_self [n * D + k] = (__bf16)W_self [k * D + n];
        Wt_neigh[n * D + k] = (__bf16)W_neigh[k * D + n];
    }
}

// ---------------------------------------------------------------------------
// Kernel 2 (fused neigh + gemm, LDS-staged): block = 256 threads, 16 dst rows.
// Phase 1 (gather, R4 shape): group g = 16 lanes per row; lane covers 8 cols
// (16 B) -> each edge access is a coalesced 256 B segment; predicated
// unroll-8 keeps 8 independent loads in flight; uniform trip count within a
// group. Mean written as bf16x8 into a 16x128 LDS tile (padded pitch).
// Phase 2 (gemm): wave w computes n-blocks {2w, 2w+1} for all 16 rows.
// A-frag (neigh) from LDS, A-frag (self) from feat_bf global, B-frags from
// L2-hot Wt. MFMA layouts (HW-verified rounds 1-5):
//   A: lane holds A[m = lane&15][k = (lane>>4)*8 + j]
//   C/D: col = lane&15, row = (lane>>4)*4 + reg
// ---------------------------------------------------------------------------
__global__ __launch_bounds__(256) void fused_kernel(
    const __bf16* __restrict__ feat_bf,
    const int*    __restrict__ src,
    const int*    __restrict__ row_start,
    const __bf16* __restrict__ Wt_self,   // bf16 [n][k]
    const __bf16* __restrict__ Wt_neigh,  // bf16 [n][k]
    const float*  __restrict__ b_self,
    const float*  __restrict__ b_neigh,
    float*        __restrict__ out)
{
    __shared__ __bf16 hs[16 * HPITCH];    // 4.25 KB

    const int t       = threadIdx.x;
    const int rowbase = blockIdx.x * 16;

    // ---- phase 1: gather (group-coalesced) -------------------------------
    {
        const int g    = t >> 4;          // group 0..15 -> row
        const int lane = t & 15;
        const int row  = rowbase + g;
        const int s0   = row_start[row];
        const int s1   = row_start[row + 1];
        const int co   = lane * 8;

        float acc[8] = {0.f, 0.f, 0.f, 0.f, 0.f, 0.f, 0.f, 0.f};

        for (int base = s0; base < s1; base += 8) {
            int idx[8];
            #pragma unroll
            for (int j = 0; j < 8; ++j) {
                const int e = base + j;
                idx[j] = src[e < s1 ? e : s1 - 1];
            }
            bf16x8 v[8];
            #pragma unroll
            for (int j = 0; j < 8; ++j)
                v[j] = *(const bf16x8*)&feat_bf[(size_t)idx[j] * D + co];
            #pragma unroll
            for (int j = 0; j < 8; ++j) {
                const float m = (base + j < s1) ? 1.0f : 0.0f;
                #pragma unroll
                for (int c = 0; c < 8; ++c)
                    acc[c] = fmaf(m, (float)v[j][c], acc[c]);
            }
        }

        const float inv = 1.0f / fmaxf((float)(s1 - s0), 1.0f);
        bf16x8 o;
        #pragma unroll
        for (int c = 0; c < 8; ++c) o[c] = (__bf16)(acc[c] * inv);
        *(bf16x8*)&hs[g * HPITCH + co] = o;
    }
    __syncthreads();

    // ---- phase 2: gemm ---------------------------------------------------
    const int w    = t >> 6;          // wave 0..3 -> n-blocks 2w, 2w+1
    const int l    = t & 63;
    const int m16  = l & 15;
    const int quad = l >> 4;
    const int kb   = quad * 8;

    // A-frags: neigh from LDS, self from global
    bf16x8 aN[4], aS[4];
    #pragma unroll
    for (int ks = 0; ks < 4; ++ks) {
        aN[ks] = *(const bf16x8*)&hs[m16 * HPITCH + ks * 32 + kb];
        aS[ks] = *(const bf16x8*)&feat_bf[(size_t)(rowbase + m16) * D + ks * 32 + kb];
    }

    f32x4 acc[2];
    #pragma unroll
    for (int nbl = 0; nbl < 2; ++nbl) {
        const int nb = w * 2 + nbl;
        f32x4 a = (f32x4){0.f, 0.f, 0.f, 0.f};
        #pragma unroll
        for (int ks = 0; ks < 4; ++ks) {
            const bf16x8 bS = *(const bf16x8*)&Wt_self [(size_t)(nb * 16 + m16) * D + ks * 32 + kb];
            a = __builtin_amdgcn_mfma_f32_16x16x32_bf16(aS[ks], bS, a, 0, 0, 0);
        }
        #pragma unroll
        for (int ks = 0; ks < 4; ++ks) {
            const bf16x8 bN = *(const bf16x8*)&Wt_neigh[(size_t)(nb * 16 + m16) * D + ks * 32 + kb];
            a = __builtin_amdgcn_mfma_f32_16x16x32_bf16(aN[ks], bN, a, 0, 0, 0);
        }
        acc[nbl] = a;
    }

    // ---- epilogue --------------------------------------------------------
    #pragma unroll
    for (int nbl = 0; nbl < 2; ++nbl) {
        const int nb   = w * 2 + nbl;
        const int col  = nb * 16 + m16;
        const float bias = b_self[col] + b_neigh[col];
        const int orow0 = rowbase + quad * 4;
        #pragma unroll
        for (int r = 0; r < 4; ++r)
            out[(size_t)(orow0 + r) * D + col] = acc[nbl][r] + bias;
    }
}

// ---------------------------------------------------------------------------
extern "C" void kernel_launch(void* const* d_in, const int* in_sizes, int n_in,
                              void* d_out, int out_size, void* d_ws, size_t ws_size,
                              hipStream_t stream)
{
    const float* feat    = (const float*)d_in[0];
    const float* W_self  = (const float*)d_in[1];
    const float* b_self  = (const float*)d_in[2];
    const float* W_neigh = (const float*)d_in[3];
    const float* b_neigh = (const float*)d_in[4];
    const int*   src_idx = (const int*)d_in[5];
    const int*   dst_idx = (const int*)d_in[6];
    const int n_edges = in_sizes[5];

    // workspace layout
    char* ws = (char*)d_ws;
    __bf16* feat_bf   = (__bf16*)ws;                                 // 32 MB
    int*    row_start = (int*)(feat_bf + (size_t)N_SRC * D);         // 256 KB
    __bf16* Wt_self   = (__bf16*)(row_start + N_DST + 16);
    __bf16* Wt_neigh  = Wt_self + D * D;

    const int n_bnd = (n_edges + 255) / 256;
    prep_kernel<<<CONV_BLOCKS + n_bnd + W_BLOCKS, 256, 0, stream>>>(
        feat, dst_idx, n_edges, n_bnd, W_self, W_neigh,
        feat_bf, row_start, Wt_self, Wt_neigh);

    fused_kernel<<<N_DST / 16, 256, 0, stream>>>(
        feat_bf, src_idx, row_start, Wt_self, Wt_neigh, b_self, b_neigh,
        (float*)d_out);
}

// Round 7
// 170.375 us; speedup vs baseline: 1.0298x; 1.0210x over previous
//
#include <hip/hip_runtime.h>
#include <hip/hip_bf16.h>

#define N_SRC   131072
#define N_DST   65536
#define D       128      // D_IN == D_OUT == 128

typedef __bf16 bf16x8 __attribute__((ext_vector_type(8)));
typedef float  f32x4  __attribute__((ext_vector_type(4)));

#define W_BLOCKS 64     // 64*256 = 16384 = D*D elements

// ---------------------------------------------------------------------------
// Kernel 1 (prep): role-split grid. NO feat conversion (the gather is
// random-line latency-bound, not byte-bound: fp32 gather 44us vs bf16 ~40us
// measured R2/R4 — the 96 MB conversion stream cost more than it saved).
//  blocks [0, n_bnd)        : sorted dst -> CSR row_start
//  blocks [n_bnd, n_bnd+64) : W fp32 [k][n] -> Wt bf16 [n][k]
// ---------------------------------------------------------------------------
__global__ __launch_bounds__(256) void prep_kernel(
    const int*   __restrict__ dst, int n_edges, int n_bnd_blocks,
    const float* __restrict__ W_self, const float* __restrict__ W_neigh,
    int*    __restrict__ row_start,
    __bf16* __restrict__ Wt_self, __bf16* __restrict__ Wt_neigh)
{
    const int b = blockIdx.x;
    const int t = threadIdx.x;

    if (b < n_bnd_blocks) {
        const int e = b * 256 + t;
        if (e < n_edges) {
            const int d    = dst[e];
            const int prev = (e == 0) ? -1 : dst[e - 1];
            for (int r = prev + 1; r <= d; ++r) row_start[r] = e;
            if (e == n_edges - 1)
                for (int r = d + 1; r <= N_DST; ++r) row_start[r] = n_edges;
        }
    } else {
        const int wb  = b - n_bnd_blocks;                // 0..63
        const int idx = wb * 256 + t;                    // 0..16383
        const int k = idx >> 7, n = idx & 127;
        Wt_self [n * D + k] = (__bf16)W_self [k * D + n];
        Wt_neigh[n * D + k] = (__bf16)W_neigh[k * D + n];
    }
}

// ---------------------------------------------------------------------------
// Kernel 2: neighbor mean over fp32 feat. 16-lane group per dst row; lane
// covers 8 cols via two float4 loads (32 B) -> full 512 B row per access.
// Predicated unroll-8: every chunk issues 8 idx loads then 16 independent
// float4 loads; mask-FMA accumulate, no serial remainder. bf16 output.
// ---------------------------------------------------------------------------
__global__ __launch_bounds__(256) void neigh_kernel(
    const float* __restrict__ feat,
    const int*   __restrict__ src,
    const int*   __restrict__ row_start,
    __bf16*      __restrict__ h_neigh)
{
    const int g    = threadIdx.x >> 4;        // group 0..15
    const int lane = threadIdx.x & 15;
    const int row  = blockIdx.x * 16 + g;
    const int s0   = row_start[row];
    const int s1   = row_start[row + 1];
    const int co   = lane * 8;                // float col offset

    float acc[8] = {0.f, 0.f, 0.f, 0.f, 0.f, 0.f, 0.f, 0.f};

    for (int base = s0; base < s1; base += 8) {
        int idx[8];
        #pragma unroll
        for (int j = 0; j < 8; ++j) {
            const int e = base + j;
            idx[j] = src[e < s1 ? e : s1 - 1];
        }
        float4 va[8], vb[8];
        #pragma unroll
        for (int j = 0; j < 8; ++j) {
            const float* p = &feat[(size_t)idx[j] * D + co];
            va[j] = *(const float4*)p;
            vb[j] = *(const float4*)(p + 4);
        }
        #pragma unroll
        for (int j = 0; j < 8; ++j) {
            const float m = (base + j < s1) ? 1.0f : 0.0f;
            acc[0] = fmaf(m, va[j].x, acc[0]);
            acc[1] = fmaf(m, va[j].y, acc[1]);
            acc[2] = fmaf(m, va[j].z, acc[2]);
            acc[3] = fmaf(m, va[j].w, acc[3]);
            acc[4] = fmaf(m, vb[j].x, acc[4]);
            acc[5] = fmaf(m, vb[j].y, acc[5]);
            acc[6] = fmaf(m, vb[j].z, acc[6]);
            acc[7] = fmaf(m, vb[j].w, acc[7]);
        }
    }

    const float inv = 1.0f / fmaxf((float)(s1 - s0), 1.0f);
    bf16x8 o;
    #pragma unroll
    for (int c = 0; c < 8; ++c) o[c] = (__bf16)(acc[c] * inv);
    *(bf16x8*)&h_neigh[(size_t)row * D + co] = o;
}

// ---------------------------------------------------------------------------
// Kernel 3: out = feat[:N_DST] @ W_self + h_neigh @ W_neigh + biases.
// MFMA bf16 16x16x32, fp32 accumulate. No LDS, no barriers.
// Self-phase A-frags: fp32 feat load + in-register bf16 convert (R1-proven).
// Fragment layouts (HW-verified rounds 1-6):
//   A: lane holds A[m = lane&15][k = (lane>>4)*8 + j]
//   B: lane holds B[k = (lane>>4)*8 + j][n = lane&15]   (from Wt[n][k])
//   C/D: col = lane&15, row = (lane>>4)*4 + reg
// ---------------------------------------------------------------------------
#define MREP 2

__global__ __launch_bounds__(256) void gemm_kernel(
    const float*  __restrict__ feat,      // fp32, first N_DST rows used
    const __bf16* __restrict__ h_neigh,   // bf16 N_DST x D
    const __bf16* __restrict__ Wt_self,   // bf16 [n][k]
    const __bf16* __restrict__ Wt_neigh,  // bf16 [n][k]
    const float*  __restrict__ b_self,
    const float*  __restrict__ b_neigh,
    float*        __restrict__ out)
{
    const int t    = threadIdx.x;
    const int w    = t >> 6;          // wave 0..3
    const int l    = t & 63;
    const int m16  = l & 15;
    const int quad = l >> 4;          // 0..3
    const int kb   = quad * 8;
    const int rowbase = blockIdx.x * (64 * MREP) + w * (16 * MREP);

    f32x4 acc[MREP][8];
    #pragma unroll
    for (int rp = 0; rp < MREP; ++rp)
        #pragma unroll
        for (int nb = 0; nb < 8; ++nb)
            acc[rp][nb] = (f32x4){0.f, 0.f, 0.f, 0.f};

    // ---- phase 0: A = feat (fp32 -> bf16 in-register) --------------------
    #pragma unroll
    for (int ks = 0; ks < 4; ++ks) {
        bf16x8 afrag[MREP];
        #pragma unroll
        for (int rp = 0; rp < MREP; ++rp) {
            const float* ap = &feat[(size_t)(rowbase + rp * 16 + m16) * D + ks * 32 + kb];
            const float4 a0 = *(const float4*)ap;
            const float4 a1 = *(const float4*)(ap + 4);
            afrag[rp][0] = (__bf16)a0.x; afrag[rp][1] = (__bf16)a0.y;
            afrag[rp][2] = (__bf16)a0.z; afrag[rp][3] = (__bf16)a0.w;
            afrag[rp][4] = (__bf16)a1.x; afrag[rp][5] = (__bf16)a1.y;
            afrag[rp][6] = (__bf16)a1.z; afrag[rp][7] = (__bf16)a1.w;
        }
        #pragma unroll
        for (int nb = 0; nb < 8; ++nb) {
            const bf16x8 bfrag = *(const bf16x8*)&Wt_self[(size_t)(nb * 16 + m16) * D + ks * 32 + kb];
            #pragma unroll
            for (int rp = 0; rp < MREP; ++rp)
                acc[rp][nb] = __builtin_amdgcn_mfma_f32_16x16x32_bf16(
                    afrag[rp], bfrag, acc[rp][nb], 0, 0, 0);
        }
    }

    // ---- phase 1: A = h_neigh (bf16 direct) ------------------------------
    #pragma unroll
    for (int ks = 0; ks < 4; ++ks) {
        bf16x8 afrag[MREP];
        #pragma unroll
        for (int rp = 0; rp < MREP; ++rp)
            afrag[rp] = *(const bf16x8*)&h_neigh[(size_t)(rowbase + rp * 16 + m16) * D + ks * 32 + kb];
        #pragma unroll
        for (int nb = 0; nb < 8; ++nb) {
            const bf16x8 bfrag = *(const bf16x8*)&Wt_neigh[(size_t)(nb * 16 + m16) * D + ks * 32 + kb];
            #pragma unroll
            for (int rp = 0; rp < MREP; ++rp)
                acc[rp][nb] = __builtin_amdgcn_mfma_f32_16x16x32_bf16(
                    afrag[rp], bfrag, acc[rp][nb], 0, 0, 0);
        }
    }

    // ---- epilogue --------------------------------------------------------
    #pragma unroll
    for (int nb = 0; nb < 8; ++nb) {
        const int col  = nb * 16 + m16;
        const float bias = b_self[col] + b_neigh[col];
        #pragma unroll
        for (int rp = 0; rp < MREP; ++rp) {
            const int orow0 = rowbase + rp * 16 + quad * 4;
            #pragma unroll
            for (int r = 0; r < 4; ++r)
                out[(size_t)(orow0 + r) * D + col] = acc[rp][nb][r] + bias;
        }
    }
}

// ---------------------------------------------------------------------------
extern "C" void kernel_launch(void* const* d_in, const int* in_sizes, int n_in,
                              void* d_out, int out_size, void* d_ws, size_t ws_size,
                              hipStream_t stream)
{
    const float* feat    = (const float*)d_in[0];
    const float* W_self  = (const float*)d_in[1];
    const float* b_self  = (const float*)d_in[2];
    const float* W_neigh = (const float*)d_in[3];
    const float* b_neigh = (const float*)d_in[4];
    const int*   src_idx = (const int*)d_in[5];
    const int*   dst_idx = (const int*)d_in[6];
    const int n_edges = in_sizes[5];

    // workspace layout
    char* ws = (char*)d_ws;
    __bf16* h_neigh   = (__bf16*)ws;                                 // 16 MB
    int*    row_start = (int*)(h_neigh + (size_t)N_DST * D);         // 256 KB
    __bf16* Wt_self   = (__bf16*)(row_start + N_DST + 16);
    __bf16* Wt_neigh  = Wt_self + D * D;

    const int n_bnd = (n_edges + 255) / 256;
    prep_kernel<<<n_bnd + W_BLOCKS, 256, 0, stream>>>(
        dst_idx, n_edges, n_bnd, W_self, W_neigh,
        row_start, Wt_self, Wt_neigh);

    neigh_kernel<<<N_DST / 16, 256, 0, stream>>>(feat, src_idx, row_start, h_neigh);

    gemm_kernel<<<N_DST / (64 * MREP), 256, 0, stream>>>(
        feat, h_neigh, Wt_self, Wt_neigh, b_self, b_neigh, (float*)d_out);
}